// Round 1
// baseline (182.294 us; speedup 1.0000x reference)
//
#include <hip/hip_runtime.h>

// ---------------- geometry ----------------
#define NTOK 49      // tokens per window
#define MPAD 64      // padded token dim for MFMA tiles
#define DIMC 128
#define NH   4
#define HD   32
#define NWIN 64
#define NBLK 4096    // B_ = BATCH * NW

// ws layout (bytes):
//   wqkv  : bf16[4*24*64*8]   = 49152 el -> 98304 B  @ 0
//   wproj : bf16[4*8*64*8]    = 16384 el -> 32768 B  @ 98304
//   bm    : f32 [64*4*2401]   = 614656 el -> 2458624 B @ 131072
#define WQKV_ELS  (4*24*64*8)
#define WPROJ_OFF 98304
#define BM_OFF    131072

typedef unsigned short u16x8 __attribute__((ext_vector_type(8)));
typedef __bf16        bf16x8 __attribute__((ext_vector_type(8)));
typedef float         f32x4  __attribute__((ext_vector_type(4)));

__device__ __forceinline__ unsigned short f2bf(float f) {
  // round-to-nearest-even float -> bf16 bits (inputs are finite)
  unsigned int u = __float_as_uint(f);
  u += 0x7fffu + ((u >> 16) & 1u);
  return (unsigned short)(u >> 16);
}

__device__ __forceinline__ bf16x8 ld_frag(const unsigned short* p) {
  return __builtin_bit_cast(bf16x8, *(const u16x8*)p);
}

#define MFMA(a, b, c) __builtin_amdgcn_mfma_f32_16x16x32_bf16(a, b, c, 0, 0, 0)

// ---------------- prep: pack weights + fuse mask/bias ----------------
__global__ void prep_kernel(const float* __restrict__ qkv_w,   // [128][384]
                            const float* __restrict__ proj_w,  // [128][128]
                            const float* __restrict__ bias_table, // [169][4]
                            const int*   __restrict__ rel_idx,    // [49*49]
                            const float* __restrict__ mask,       // [64][49][49]
                            unsigned short* __restrict__ wqkv,
                            unsigned short* __restrict__ wproj,
                            float* __restrict__ bm)
{
  const int tid = blockIdx.x * blockDim.x + threadIdx.x;
  const int nth = gridDim.x * blockDim.x;

  // qkv_w fragments: idx = ((kt*24 + ct)*64 + lane)*8 + ii
  for (int idx = tid; idx < 4*24*64*8; idx += nth) {
    int ii = idx & 7, lane = (idx >> 3) & 63, rest = idx >> 9;
    int ct = rest % 24, kt = rest / 24;
    int k = kt*32 + ((lane >> 4) << 3) + ii;
    int c = ct*16 + (lane & 15);
    wqkv[idx] = f2bf(qkv_w[k*384 + c]);
  }
  // proj_w fragments: idx = ((kt*8 + ct)*64 + lane)*8 + ii
  for (int idx = tid; idx < 4*8*64*8; idx += nth) {
    int ii = idx & 7, lane = (idx >> 3) & 63, rest = idx >> 9;
    int ct = rest & 7, kt = rest >> 3;
    int k = kt*32 + ((lane >> 4) << 3) + ii;
    int c = ct*16 + (lane & 15);
    wproj[idx] = f2bf(proj_w[k*128 + c]);
  }
  // bm[(wi*4 + h)*2401 + nm] = mask[wi][nm] + bias_table[rel_idx[nm]][h]
  for (int idx = tid; idx < NWIN*NH*NTOK*NTOK; idx += nth) {
    int nm = idx % 2401;
    int rest = idx / 2401;
    int h = rest & 3, wi = rest >> 2;
    bm[idx] = mask[wi*2401 + nm] + bias_table[rel_idx[nm]*4 + h];
  }
}

// ---------------- fused window attention ----------------
// LDS (ushort elements):
//   xs : [64][136]                      8704 el  @0      (X, later attn-out)
//   qk : [h][ Q[64][40] | K[64][40] ]   20480 el @8704   (P[64][72] aliases per-head slot)
//   vt : [h][32][72]                    9216 el  @29184  (V transposed)
// total 38400 el = 76800 B -> 2 blocks/CU
__global__ __launch_bounds__(256, 2) void winattn_kernel(
    const float* __restrict__ x,
    const float* __restrict__ qkv_b,
    const float* __restrict__ proj_b,
    const unsigned short* __restrict__ wqkv,
    const unsigned short* __restrict__ wproj,
    const float* __restrict__ bm,
    float* __restrict__ out)
{
  __shared__ __align__(16) unsigned short smem[38400];
  unsigned short* xs = smem;
  unsigned short* qk = smem + 8704;
  unsigned short* vt = smem + 29184;

  const int b    = blockIdx.x;
  const int wi   = b & (NWIN - 1);
  const int tid  = threadIdx.x;
  const int wave = tid >> 6;
  const int lane = tid & 63;
  const int lhi  = lane >> 4;   // 0..3
  const int llo  = lane & 15;   // 0..15

  // ---- load x -> xs (bf16), zero pad rows 49..63 ----
  {
    const float4* xv = (const float4*)(x + (size_t)b * (NTOK*DIMC));
    for (int idx = tid; idx < 64*32; idx += 256) {
      int n = idx >> 5, c4 = (idx & 31) << 2;
      float4 v = make_float4(0.f, 0.f, 0.f, 0.f);
      if (n < NTOK) v = xv[n*32 + (idx & 31)];
      unsigned short* p = xs + n*136 + c4;
      p[0] = f2bf(v.x); p[1] = f2bf(v.y); p[2] = f2bf(v.z); p[3] = f2bf(v.w);
    }
  }
  __syncthreads();

  const f32x4 zv = {0.f, 0.f, 0.f, 0.f};

  // ---- QKV GEMM: C[64][384] = xs @ qkv_w ; wave handles cols [wave*96, +96) ----
  {
    f32x4 acc[4][6];
    #pragma unroll
    for (int i = 0; i < 4; i++)
      #pragma unroll
      for (int j = 0; j < 6; j++) acc[i][j] = zv;

    #pragma unroll
    for (int kt = 0; kt < 4; kt++) {
      bf16x8 a[4];
      #pragma unroll
      for (int i = 0; i < 4; i++)
        a[i] = ld_frag(xs + (i*16 + llo)*136 + kt*32 + lhi*8);
      #pragma unroll
      for (int j = 0; j < 6; j++) {
        int ct = wave*6 + j;
        bf16x8 bw = ld_frag(wqkv + (((kt*24 + ct)*64 + lane) << 3));
        #pragma unroll
        for (int i = 0; i < 4; i++) acc[i][j] = MFMA(a[i], bw, acc[i][j]);
      }
    }

    // epilogue: +bias, scale q, scatter to Q/K/Vt tiles
    const float scale = 0.17677669529663687f;  // 32^-0.5
    #pragma unroll
    for (int j = 0; j < 6; j++) {
      int cbase = (wave*6 + j)*16 + llo;       // 0..383, uniform tile per j
      float bias = qkv_b[cbase];
      int mat = cbase >> 7;                    // 0=q 1=k 2=v
      int cc  = cbase & 127;
      int hh = cc >> 5, d = cc & 31;
      #pragma unroll
      for (int i = 0; i < 4; i++) {
        #pragma unroll
        for (int r2 = 0; r2 < 4; r2++) {
          int r = i*16 + lhi*4 + r2;
          float v = acc[i][j][r2] + bias;
          if (mat == 0)      qk[hh*5120 + r*40 + d] = f2bf(v * scale);
          else if (mat == 1) qk[hh*5120 + 2560 + r*40 + d] = f2bf(v);
          else               vt[hh*2304 + d*72 + r] = f2bf(v);
        }
      }
    }
  }
  __syncthreads();

  // ---- attention: wave == head ----
  f32x4 oacc[4][2];
  {
    const int h = wave;
    const unsigned short* Qh = qk + h*5120;
    const unsigned short* Kh = qk + h*5120 + 2560;
    const unsigned short* Vh = vt + h*2304;
    unsigned short*       Ph = qk + h*5120;   // P[64][72] aliases own Q/K slot

    // QK^T
    f32x4 s[4][4];
    #pragma unroll
    for (int i = 0; i < 4; i++)
      #pragma unroll
      for (int j = 0; j < 4; j++) s[i][j] = zv;

    bf16x8 qa[4];
    #pragma unroll
    for (int i = 0; i < 4; i++) qa[i] = ld_frag(Qh + (i*16 + llo)*40 + lhi*8);
    #pragma unroll
    for (int j = 0; j < 4; j++) {
      bf16x8 kb = ld_frag(Kh + (j*16 + llo)*40 + lhi*8);
      #pragma unroll
      for (int i = 0; i < 4; i++) s[i][j] = MFMA(qa[i], kb, s[i][j]);
    }

    // + (mask + rel-pos bias), mask out pad cols
    const float* bmp = bm + (size_t)(wi*4 + h) * 2401;
    #pragma unroll
    for (int i = 0; i < 4; i++) {
      #pragma unroll
      for (int r2 = 0; r2 < 4; r2++) {
        int r = i*16 + lhi*4 + r2;
        #pragma unroll
        for (int j = 0; j < 4; j++) {
          int c = j*16 + llo;
          float v = s[i][j][r2];
          v = (r < NTOK && c < NTOK) ? v + bmp[r*49 + c] : -1e30f;
          s[i][j][r2] = v;
        }
      }
    }

    // row softmax (row lives in 16 lanes sharing lhi, across 4 j-regs)
    #pragma unroll
    for (int i = 0; i < 4; i++) {
      #pragma unroll
      for (int r2 = 0; r2 < 4; r2++) {
        float m = s[i][0][r2];
        m = fmaxf(m, s[i][1][r2]);
        m = fmaxf(m, s[i][2][r2]);
        m = fmaxf(m, s[i][3][r2]);
        #pragma unroll
        for (int off = 1; off < 16; off <<= 1) m = fmaxf(m, __shfl_xor(m, off, 64));
        float sum = 0.f;
        #pragma unroll
        for (int j = 0; j < 4; j++) {
          float p = __expf(s[i][j][r2] - m);
          s[i][j][r2] = p;
          sum += p;
        }
        #pragma unroll
        for (int off = 1; off < 16; off <<= 1) sum += __shfl_xor(sum, off, 64);
        float inv = 1.0f / sum;
        #pragma unroll
        for (int j = 0; j < 4; j++) s[i][j][r2] *= inv;
      }
    }

    // P -> LDS (bf16)
    #pragma unroll
    for (int i = 0; i < 4; i++) {
      #pragma unroll
      for (int r2 = 0; r2 < 4; r2++) {
        int r = i*16 + lhi*4 + r2;
        #pragma unroll
        for (int j = 0; j < 4; j++)
          Ph[r*72 + j*16 + llo] = f2bf(s[i][j][r2]);
      }
    }
    __syncthreads();   // orders P writes before frag reads (and is uniform)

    // PV: O[64][32] = P[64][64] @ V[64][32]
    #pragma unroll
    for (int i = 0; i < 4; i++)
      #pragma unroll
      for (int nt = 0; nt < 2; nt++) oacc[i][nt] = zv;

    #pragma unroll
    for (int ks = 0; ks < 2; ks++) {
      bf16x8 pa[4];
      #pragma unroll
      for (int i = 0; i < 4; i++) pa[i] = ld_frag(Ph + (i*16 + llo)*72 + ks*32 + lhi*8);
      #pragma unroll
      for (int nt = 0; nt < 2; nt++) {
        bf16x8 vb = ld_frag(Vh + (nt*16 + llo)*72 + ks*32 + lhi*8);
        #pragma unroll
        for (int i = 0; i < 4; i++) oacc[i][nt] = MFMA(pa[i], vb, oacc[i][nt]);
      }
    }
  }

  // ---- attn-out -> xs (bf16), cols [wave*32, +32) ----
  #pragma unroll
  for (int i = 0; i < 4; i++) {
    #pragma unroll
    for (int nt = 0; nt < 2; nt++) {
      #pragma unroll
      for (int r2 = 0; r2 < 4; r2++) {
        int r = i*16 + lhi*4 + r2;
        xs[r*136 + wave*32 + nt*16 + llo] = f2bf(oacc[i][nt][r2]);
      }
    }
  }
  __syncthreads();

  // ---- proj: out[64][128] = attn_out @ proj_w + proj_b ----
  {
    f32x4 acc[4][2];
    #pragma unroll
    for (int i = 0; i < 4; i++)
      #pragma unroll
      for (int j = 0; j < 2; j++) acc[i][j] = zv;

    #pragma unroll
    for (int kt = 0; kt < 4; kt++) {
      bf16x8 a[4];
      #pragma unroll
      for (int i = 0; i < 4; i++)
        a[i] = ld_frag(xs + (i*16 + llo)*136 + kt*32 + lhi*8);
      #pragma unroll
      for (int j = 0; j < 2; j++) {
        int ct = wave*2 + j;
        bf16x8 bw = ld_frag(wproj + (((kt*8 + ct)*64 + lane) << 3));
        #pragma unroll
        for (int i = 0; i < 4; i++) acc[i][j] = MFMA(a[i], bw, acc[i][j]);
      }
    }

    float* op = out + (size_t)b * (NTOK*DIMC);
    #pragma unroll
    for (int j = 0; j < 2; j++) {
      int c = (wave*2 + j)*16 + llo;
      float pb = proj_b[c];
      #pragma unroll
      for (int i = 0; i < 4; i++) {
        #pragma unroll
        for (int r2 = 0; r2 < 4; r2++) {
          int r = i*16 + lhi*4 + r2;
          if (r < NTOK) op[r*128 + c] = acc[i][j][r2] + pb;
        }
      }
    }
  }
}

extern "C" void kernel_launch(void* const* d_in, const int* in_sizes, int n_in,
                              void* d_out, int out_size, void* d_ws, size_t ws_size,
                              hipStream_t stream)
{
  const float* x          = (const float*)d_in[0];
  const float* mask       = (const float*)d_in[1];
  const float* qkv_w      = (const float*)d_in[2];
  const float* qkv_b      = (const float*)d_in[3];
  const float* proj_w     = (const float*)d_in[4];
  const float* proj_b     = (const float*)d_in[5];
  const float* bias_table = (const float*)d_in[6];
  const int*   rel_idx    = (const int*)d_in[7];
  float* out = (float*)d_out;

  unsigned short* wqkv  = (unsigned short*)d_ws;
  unsigned short* wproj = (unsigned short*)((char*)d_ws + WPROJ_OFF);
  float*          bm    = (float*)((char*)d_ws + BM_OFF);

  prep_kernel<<<192, 256, 0, stream>>>(qkv_w, proj_w, bias_table, rel_idx, mask,
                                       wqkv, wproj, bm);
  winattn_kernel<<<NBLK, 256, 0, stream>>>(x, qkv_b, proj_b, wqkv, wproj, bm, out);
}